// Round 1
// baseline (394.239 us; speedup 1.0000x reference)
//
#include <hip/hip_runtime.h>
#include <cstdint>

#define DEV static __device__ __forceinline__

typedef __bf16 bf16x8 __attribute__((ext_vector_type(8)));
typedef float  f32x4  __attribute__((ext_vector_type(4)));

DEV unsigned short f32_bf16(float f) {
  union { float f; unsigned u; } v; v.f = f;
  unsigned r = v.u + 0x7FFFu + ((v.u >> 16) & 1u);
  return (unsigned short)(r >> 16);
}

DEV void gload16(const void* g, void* lds) {
  __builtin_amdgcn_global_load_lds((__attribute__((address_space(1))) void*)g,
                                   (__attribute__((address_space(3))) void*)lds,
                                   16, 0, 0);
}

// ---------------- elementwise cast fp32 -> bf16 (4 elems/thread) ----------------
__global__ void cast_bf16(const float* __restrict__ x, unsigned short* __restrict__ y) {
  int i = blockIdx.x * 256 + threadIdx.x;
  float4 v = ((const float4*)x)[i];
  uint2 o;
  o.x = (unsigned)f32_bf16(v.x) | ((unsigned)f32_bf16(v.y) << 16);
  o.y = (unsigned)f32_bf16(v.z) | ((unsigned)f32_bf16(v.w) << 16);
  ((uint2*)y)[i] = o;
}

// ---------------- tiled transpose-cast: W[K][N] fp32 -> WT[N][K] bf16 ----------------
__global__ void transpose_cast(const float* __restrict__ W, unsigned short* __restrict__ WT,
                               int K, int N) {
  __shared__ float t[64][65];
  int k0 = blockIdx.x * 64, n0 = blockIdx.y * 64;
  int tn = threadIdx.x & 63, tk = threadIdx.x >> 6;
#pragma unroll
  for (int i = 0; i < 64; i += 4)
    t[tk + i][tn] = W[(size_t)(k0 + tk + i) * N + n0 + tn];
  __syncthreads();
  int k2 = (threadIdx.x & 31) * 2, n = threadIdx.x >> 5;
#pragma unroll
  for (int i = 0; i < 64; i += 8) {
    int nn = n + i;
    unsigned o = (unsigned)f32_bf16(t[k2][nn]) | ((unsigned)f32_bf16(t[k2 + 1][nn]) << 16);
    *(unsigned*)&WT[(size_t)(n0 + nn) * K + k0 + k2] = o;
  }
}

// ---------------- mask uniformity check: flag=1 if any mask element != 1.0f ----------------
__global__ void mask_check(const float* __restrict__ m, int* __restrict__ flag) {
  size_t i = ((size_t)blockIdx.x * 256 + threadIdx.x) * 4;
  float4 v = *(const float4*)(m + i);
  if (v.x != 1.0f || v.y != 1.0f || v.z != 1.0f || v.w != 1.0f) atomicOr(flag, 1);
}

// ---------------- GEMM: C[M][N] = A[M][K] * BT[N][K]^T  (bf16 in, bf16/f32 out) ----------------
// m97 pattern: 128x128 tile, BK=32, 4 waves (2x2), global_load_lds width-16 staging,
// 2-bit XOR chunk swizzle to reduce ds_read_b128 bank conflicts.
template <int OUT_BF16>
__global__ void __launch_bounds__(256) gemm_bt(const unsigned short* __restrict__ A,
                                               const unsigned short* __restrict__ BT,
                                               void* __restrict__ Cout,
                                               int M, int N, int K) {
  __shared__ __align__(16) unsigned short As[128 * 32];
  __shared__ __align__(16) unsigned short Bs[128 * 32];
  const int tid = threadIdx.x, wave = tid >> 6, lane = tid & 63;
  const int l = lane & 15, quad = lane >> 4;
  const int wm = (wave & 1) * 64, wn = (wave >> 1) * 64;
  const int bm = blockIdx.x, bn = blockIdx.y;

  const int srow = wave * 32 + (lane >> 2);            // staging row within tile
  const int sswz = ((lane & 3) ^ (srow & 3)) * 8;      // swizzled source chunk
  const unsigned short* pA = A + (size_t)(bm * 128 + srow) * K + sswz;
  const unsigned short* pB = BT + (size_t)(bn * 128 + srow) * K + sswz;
  unsigned short* ldsA0 = &As[(wave * 32) * 32];
  unsigned short* ldsA1 = &As[(wave * 32 + 16) * 32];
  unsigned short* ldsB0 = &Bs[(wave * 32) * 32];
  unsigned short* ldsB1 = &Bs[(wave * 32 + 16) * 32];

  f32x4 acc[4][4];
#pragma unroll
  for (int i = 0; i < 4; i++)
#pragma unroll
    for (int j = 0; j < 4; j++) { f32x4 z = {0.f, 0.f, 0.f, 0.f}; acc[i][j] = z; }

  for (int kt = 0; kt < K; kt += 32) {
    __syncthreads();
    gload16(pA, ldsA0);
    gload16(pA + (size_t)16 * K, ldsA1);
    gload16(pB, ldsB0);
    gload16(pB + (size_t)16 * K, ldsB1);
    pA += 32; pB += 32;
    __syncthreads();
    bf16x8 af[4], bv[4];
#pragma unroll
    for (int mt = 0; mt < 4; mt++) {
      int r = wm + mt * 16 + l;
      af[mt] = *(const bf16x8*)&As[r * 32 + ((quad ^ (r & 3)) * 8)];
    }
#pragma unroll
    for (int nt = 0; nt < 4; nt++) {
      int r = wn + nt * 16 + l;
      bv[nt] = *(const bf16x8*)&Bs[r * 32 + ((quad ^ (r & 3)) * 8)];
    }
#pragma unroll
    for (int mt = 0; mt < 4; mt++)
#pragma unroll
      for (int nt = 0; nt < 4; nt++)
        acc[mt][nt] = __builtin_amdgcn_mfma_f32_16x16x32_bf16(af[mt], bv[nt], acc[mt][nt], 0, 0, 0);
  }
  // epilogue: C/D layout col = lane&15, row = quad*4 + r
#pragma unroll
  for (int mt = 0; mt < 4; mt++)
#pragma unroll
    for (int nt = 0; nt < 4; nt++)
#pragma unroll
      for (int r = 0; r < 4; r++) {
        int row = bm * 128 + wm + mt * 16 + quad * 4 + r;
        int col = bn * 128 + wn + nt * 16 + l;
        if (OUT_BF16)
          ((unsigned short*)Cout)[(size_t)row * N + col] = f32_bf16(acc[mt][nt][r]);
        else
          ((float*)Cout)[(size_t)row * N + col] = acc[mt][nt][r];
      }
}

// ---------------- fused flash attention with T5 relative position bias ----------------
// grid: 512 = 32 (b,h) x 16 q-tiles; block 256 = 4 waves, each owns 32 q-rows.
__global__ void __launch_bounds__(256, 2) attn(const unsigned short* __restrict__ qkv,
                                               const float* __restrict__ mask,
                                               const float* __restrict__ emb,
                                               const int* __restrict__ mflag,
                                               unsigned short* __restrict__ ctx) {
  __shared__ __align__(16) unsigned short Ks[128 * 64];
  __shared__ __align__(16) unsigned short VTs[64 * 136];   // V transposed, padded (+8)
  __shared__ __align__(16) unsigned short Pb[4 * 32 * 136]; // per-wave P, padded; aliased for Q staging
  __shared__ float lutU[32];
  __shared__ float lutM[32];

  const float LOG2E = 1.4426950408889634f;
  const int tid = threadIdx.x, wave = tid >> 6, lane = tid & 63;
  const int l = lane & 15, quad = lane >> 4;
  const int qt = blockIdx.x & 15, bh = blockIdx.x >> 4;
  const int b = bh >> 4, h = bh & 15;
  const int q0 = qt * 128;

  if (tid < 32) {
    float v = emb[tid * 16 + h] * LOG2E;   // bias pre-scaled by log2(e)
    lutU[tid] = v;
    lutM[tid] = v - 10000.0f * LOG2E;
  }
  const int masked = *mflag;

  const unsigned short* qbase = qkv + (size_t)(b * 2048 + q0) * 3072 + h * 64;
  const unsigned short* kbase = qkv + (size_t)(b * 2048) * 3072 + 1024 + h * 64;
  const unsigned short* vbase = qkv + (size_t)(b * 2048) * 3072 + 2048 + h * 64;
  const float* mbase = mask + (size_t)b * 2048 * 2048;

  // ---- stage Q into Pb region (alias, consumed before P is first written) ----
  unsigned short* Qs = Pb;
  {
    const int rw = lane >> 3, c = lane & 7;
#pragma unroll
    for (int j = 0; j < 4; j++) {
      int row = wave * 32 + j * 8 + rw;
      gload16(qbase + (size_t)row * 3072 + ((c ^ (row & 7)) * 8), &Qs[(wave * 32 + j * 8) * 64]);
    }
  }
  __syncthreads();
  bf16x8 qf[2][2];
#pragma unroll
  for (int mt = 0; mt < 2; mt++)
#pragma unroll
    for (int ks = 0; ks < 2; ks++) {
      int m = wave * 32 + mt * 16 + l;
      qf[mt][ks] = *(const bf16x8*)&Qs[m * 64 + (((ks * 4 + quad) ^ (m & 7)) * 8)];
    }

  f32x4 Oa[2][4];
  float mr[2][4], lr[2][4];
#pragma unroll
  for (int mt = 0; mt < 2; mt++)
#pragma unroll
    for (int r = 0; r < 4; r++) { mr[mt][r] = -3.0e38f; lr[mt][r] = 0.f; }
#pragma unroll
  for (int mt = 0; mt < 2; mt++)
#pragma unroll
    for (int dt = 0; dt < 4; dt++) { f32x4 z = {0.f, 0.f, 0.f, 0.f}; Oa[mt][dt] = z; }

  unsigned short* Pw = &Pb[wave * (32 * 136)];

  for (int kt = 0; kt < 16; kt++) {
    const int k0 = kt * 128;
    __syncthreads();  // prior iteration's Ks/VTs reads done
    // ---- stage K (async, 3-bit XOR swizzle) ----
    {
      const int rw = lane >> 3, c = lane & 7;
#pragma unroll
      for (int j = 0; j < 4; j++) {
        int row = wave * 32 + j * 8 + rw;
        gload16(kbase + (size_t)(k0 + row) * 3072 + ((c ^ (row & 7)) * 8),
                &Ks[(wave * 32 + j * 8) * 64]);
      }
    }
    // ---- stage V transposed: VTs[d][k], padded row stride 136 ----
    {
      const int kp = tid & 63, dg = tid >> 6;
#pragma unroll
      for (int p = 0; p < 2; p++) {
        const int d0 = (dg + p * 4) * 8;
        const unsigned short* s0 = vbase + (size_t)(k0 + 2 * kp) * 3072 + d0;
        uint4 va = *(const uint4*)s0;
        uint4 vb = *(const uint4*)(s0 + 3072);
        const unsigned short* pa = (const unsigned short*)&va;
        const unsigned short* pb = (const unsigned short*)&vb;
#pragma unroll
        for (int j = 0; j < 8; j++)
          *(unsigned*)&VTs[(d0 + j) * 136 + 2 * kp] = (unsigned)pa[j] | ((unsigned)pb[j] << 16);
      }
    }
    __syncthreads();

    // ---- S = Q K^T (each wave: [32 q][128 k]) ----
    f32x4 sa[2][8];
#pragma unroll
    for (int nt = 0; nt < 8; nt++) {
      int n = nt * 16 + l;
      bf16x8 kf0 = *(const bf16x8*)&Ks[n * 64 + ((quad ^ (n & 7)) * 8)];
      bf16x8 kf1 = *(const bf16x8*)&Ks[n * 64 + (((4 + quad) ^ (n & 7)) * 8)];
#pragma unroll
      for (int mt = 0; mt < 2; mt++) {
        f32x4 z = {0.f, 0.f, 0.f, 0.f};
        z = __builtin_amdgcn_mfma_f32_16x16x32_bf16(qf[mt][0], kf0, z, 0, 0, 0);
        z = __builtin_amdgcn_mfma_f32_16x16x32_bf16(qf[mt][1], kf1, z, 0, 0, 0);
        sa[mt][nt] = z;
      }
    }

    // ---- scale + mask + relative-position bias (exp2 domain), track row max ----
    float rmax[2][4];
#pragma unroll
    for (int mt = 0; mt < 2; mt++)
#pragma unroll
      for (int r = 0; r < 4; r++) rmax[mt][r] = -3.0e38f;

#pragma unroll
    for (int mt = 0; mt < 2; mt++) {
#pragma unroll
      for (int nt = 0; nt < 8; nt++) {
#pragma unroll
        for (int r = 0; r < 4; r++) {
          const int qg = q0 + wave * 32 + mt * 16 + quad * 4 + r;
          const int kg = k0 + nt * 16 + l;
          int rel = kg - qg;
          int rp = rel < 0 ? -rel : rel;
          int off;
          if (rp < 8) off = rp;
          else off = 8 + (rp >= 12) + (rp >= 16) + (rp >= 23) + (rp >= 32) +
                     (rp >= 46) + (rp >= 64) + (rp >= 91);  // exact T5 bucket thresholds
          const int bucket = (rel > 0 ? 16 : 0) + off;
          float sh;
          if (masked) {
            float mv = mbase[(size_t)qg * 2048 + kg];
            sh = fmaf(sa[mt][nt][r], mv * (0.125f * LOG2E),
                      fmaf(mv, 10000.0f * LOG2E, lutM[bucket]));
          } else {
            sh = fmaf(sa[mt][nt][r], 0.125f * LOG2E, lutU[bucket]);
          }
          sa[mt][nt][r] = sh;
          rmax[mt][r] = fmaxf(rmax[mt][r], sh);
        }
      }
    }
    // row-max reduce across the 16 lanes holding each row
#pragma unroll
    for (int mt = 0; mt < 2; mt++)
#pragma unroll
      for (int r = 0; r < 4; r++) {
        float v = rmax[mt][r];
        v = fmaxf(v, __shfl_xor(v, 1, 16));
        v = fmaxf(v, __shfl_xor(v, 2, 16));
        v = fmaxf(v, __shfl_xor(v, 4, 16));
        v = fmaxf(v, __shfl_xor(v, 8, 16));
        rmax[mt][r] = v;
      }
    float alpha[2][4];
#pragma unroll
    for (int mt = 0; mt < 2; mt++)
#pragma unroll
      for (int r = 0; r < 4; r++) {
        float mn = fmaxf(mr[mt][r], rmax[mt][r]);
        float al = __builtin_amdgcn_exp2f(mr[mt][r] - mn);
        mr[mt][r] = mn; alpha[mt][r] = al; lr[mt][r] *= al;
      }
    // P = exp2(s - m): write bf16 to per-wave LDS strip, accumulate per-lane partial l
#pragma unroll
    for (int mt = 0; mt < 2; mt++)
#pragma unroll
      for (int nt = 0; nt < 8; nt++)
#pragma unroll
        for (int r = 0; r < 4; r++) {
          float p = __builtin_amdgcn_exp2f(sa[mt][nt][r] - mr[mt][r]);
          lr[mt][r] += p;
          Pw[(mt * 16 + quad * 4 + r) * 136 + nt * 16 + l] = f32_bf16(p);
        }
    // rescale O accumulator
#pragma unroll
    for (int mt = 0; mt < 2; mt++)
#pragma unroll
      for (int dt = 0; dt < 4; dt++)
#pragma unroll
        for (int r = 0; r < 4; r++) Oa[mt][dt][r] *= alpha[mt][r];

    __syncthreads();  // P visible

    // ---- O += P V ----
#pragma unroll
    for (int ks = 0; ks < 4; ks++) {
      bf16x8 pf[2], vf[4];
#pragma unroll
      for (int mt = 0; mt < 2; mt++)
        pf[mt] = *(const bf16x8*)&Pw[(mt * 16 + l) * 136 + ks * 32 + quad * 8];
#pragma unroll
      for (int dt = 0; dt < 4; dt++)
        vf[dt] = *(const bf16x8*)&VTs[(dt * 16 + l) * 136 + ks * 32 + quad * 8];
#pragma unroll
      for (int mt = 0; mt < 2; mt++)
#pragma unroll
        for (int dt = 0; dt < 4; dt++)
          Oa[mt][dt] = __builtin_amdgcn_mfma_f32_16x16x32_bf16(pf[mt], vf[dt], Oa[mt][dt], 0, 0, 0);
    }
  }

  // ---- final: reduce l across lanes, normalize, store ctx bf16 [b,s,h*d] ----
#pragma unroll
  for (int mt = 0; mt < 2; mt++)
#pragma unroll
    for (int r = 0; r < 4; r++) {
      float v = lr[mt][r];
      v += __shfl_xor(v, 1, 16);
      v += __shfl_xor(v, 2, 16);
      v += __shfl_xor(v, 4, 16);
      v += __shfl_xor(v, 8, 16);
      lr[mt][r] = 1.0f / v;
    }
#pragma unroll
  for (int mt = 0; mt < 2; mt++)
#pragma unroll
    for (int dt = 0; dt < 4; dt++)
#pragma unroll
      for (int r = 0; r < 4; r++) {
        const int qg = q0 + wave * 32 + mt * 16 + quad * 4 + r;
        ctx[(size_t)(b * 2048 + qg) * 1024 + h * 64 + dt * 16 + l] =
            f32_bf16(Oa[mt][dt][r] * lr[mt][r]);
      }
}

// ---------------- launch ----------------
extern "C" void kernel_launch(void* const* d_in, const int* in_sizes, int n_in,
                              void* d_out, int out_size, void* d_ws, size_t ws_size,
                              hipStream_t stream) {
  const float* hs   = (const float*)d_in[0];
  const float* mask = (const float*)d_in[1];
  const float* wqkv = (const float*)d_in[2];
  const float* wo   = (const float*)d_in[3];
  const float* emb  = (const float*)d_in[4];
  float* out = (float*)d_out;

  char* ws = (char*)d_ws;
  // layout (ctx aliases hiddenB: gemm1 consumes hiddenB before attn writes ctx)
  unsigned short* hB  = (unsigned short*)(ws);              //  8,388,608 B
  unsigned short* ctx = (unsigned short*)(ws);              //  (alias)
  unsigned short* wqT = (unsigned short*)(ws + 8388608);    //  6,291,456 B
  unsigned short* woT = (unsigned short*)(ws + 14680064);   //  2,097,152 B
  unsigned short* qkv = (unsigned short*)(ws + 16777216);   // 25,165,824 B
  int* mflag          = (int*)(ws + 41943040);              //          4 B
  if (ws_size < 41943044) return;  // fail loudly (absmax) rather than corrupt

  hipMemsetAsync(mflag, 0, 4, stream);
  cast_bf16<<<4096, 256, 0, stream>>>(hs, hB);                             // 4M elems
  transpose_cast<<<dim3(16, 48), 256, 0, stream>>>(wqkv, wqT, 1024, 3072);
  transpose_cast<<<dim3(16, 16), 256, 0, stream>>>(wo, woT, 1024, 1024);
  mask_check<<<8192, 256, 0, stream>>>(mask, mflag);                       // 8.4M floats
  gemm_bt<1><<<dim3(32, 24), 256, 0, stream>>>(hB, wqT, qkv, 4096, 3072, 1024);
  attn<<<512, 256, 0, stream>>>(qkv, mask, emb, mflag, ctx);
  gemm_bt<0><<<dim3(32, 8), 256, 0, stream>>>(ctx, woT, out, 4096, 1024, 1024);
}

// Round 2
// 260.681 us; speedup vs baseline: 1.5123x; 1.5123x over previous
//
#include <hip/hip_runtime.h>
#include <cstdint>

#define DEV static __device__ __forceinline__

typedef __bf16 bf16x8 __attribute__((ext_vector_type(8)));
typedef __bf16 bf16x4 __attribute__((ext_vector_type(4)));
typedef float  f32x4  __attribute__((ext_vector_type(4)));

DEV unsigned short f32_bf16(float f) {
  union { float f; unsigned u; } v; v.f = f;
  unsigned r = v.u + 0x7FFFu + ((v.u >> 16) & 1u);
  return (unsigned short)(r >> 16);
}

DEV void gload16(const void* g, void* lds) {
  __builtin_amdgcn_global_load_lds((__attribute__((address_space(1))) void*)g,
                                   (__attribute__((address_space(3))) void*)lds,
                                   16, 0, 0);
}

DEV float bcast_lane(float v, int srclane) {
  union { float f; int i; } u; u.f = v;
  u.i = __builtin_amdgcn_ds_bpermute(srclane << 2, u.i);
  return u.f;
}

// ---------------- elementwise cast fp32 -> bf16 (4 elems/thread) ----------------
__global__ void cast_bf16(const float* __restrict__ x, unsigned short* __restrict__ y) {
  int i = blockIdx.x * 256 + threadIdx.x;
  float4 v = ((const float4*)x)[i];
  uint2 o;
  o.x = (unsigned)f32_bf16(v.x) | ((unsigned)f32_bf16(v.y) << 16);
  o.y = (unsigned)f32_bf16(v.z) | ((unsigned)f32_bf16(v.w) << 16);
  ((uint2*)y)[i] = o;
}

// ---------------- tiled transpose-cast: W[K][N] fp32 -> WT[N][K] bf16 ----------------
__global__ void transpose_cast(const float* __restrict__ W, unsigned short* __restrict__ WT,
                               int K, int N) {
  __shared__ float t[64][65];
  int k0 = blockIdx.x * 64, n0 = blockIdx.y * 64;
  int tn = threadIdx.x & 63, tk = threadIdx.x >> 6;
#pragma unroll
  for (int i = 0; i < 64; i += 4)
    t[tk + i][tn] = W[(size_t)(k0 + tk + i) * N + n0 + tn];
  __syncthreads();
  int k2 = (threadIdx.x & 31) * 2, n = threadIdx.x >> 5;
#pragma unroll
  for (int i = 0; i < 64; i += 8) {
    int nn = n + i;
    unsigned o = (unsigned)f32_bf16(t[k2][nn]) | ((unsigned)f32_bf16(t[k2 + 1][nn]) << 16);
    *(unsigned*)&WT[(size_t)(n0 + nn) * K + k0 + k2] = o;
  }
}

// ---------------- mask uniformity check ----------------
__global__ void mask_check(const float* __restrict__ m, int* __restrict__ flag) {
  size_t i = ((size_t)blockIdx.x * 256 + threadIdx.x) * 4;
  float4 v = *(const float4*)(m + i);
  if (v.x != 1.0f || v.y != 1.0f || v.z != 1.0f || v.w != 1.0f) atomicOr(flag, 1);
}

// ---------------- GEMM: C[M][N] = A[M][K] * BT[N][K]^T ----------------
// MODE 0: fp32 C out. MODE 2: scatter to Qb[b,h,s,d] / Kb[b,h,s,d] / VTb[b,h,d,s].
template <int MODE>
__global__ void __launch_bounds__(256) gemm_bt(const unsigned short* __restrict__ A,
                                               const unsigned short* __restrict__ BT,
                                               float* __restrict__ Cout,
                                               unsigned short* __restrict__ Qb,
                                               unsigned short* __restrict__ Kb,
                                               unsigned short* __restrict__ VTb,
                                               int M, int N, int K) {
  __shared__ __align__(16) unsigned short As[128 * 32];
  __shared__ __align__(16) unsigned short Bs[128 * 32];
  const int tid = threadIdx.x, wave = tid >> 6, lane = tid & 63;
  const int l = lane & 15, quad = lane >> 4;
  const int wm = (wave & 1) * 64, wn = (wave >> 1) * 64;
  const int bm = blockIdx.x, bn = blockIdx.y;

  const int srow = wave * 32 + (lane >> 2);
  const int sswz = ((lane & 3) ^ (srow & 3)) * 8;
  const unsigned short* pA = A + (size_t)(bm * 128 + srow) * K + sswz;
  const unsigned short* pB = BT + (size_t)(bn * 128 + srow) * K + sswz;
  unsigned short* ldsA0 = &As[(wave * 32) * 32];
  unsigned short* ldsA1 = &As[(wave * 32 + 16) * 32];
  unsigned short* ldsB0 = &Bs[(wave * 32) * 32];
  unsigned short* ldsB1 = &Bs[(wave * 32 + 16) * 32];

  f32x4 acc[4][4];
#pragma unroll
  for (int i = 0; i < 4; i++)
#pragma unroll
    for (int j = 0; j < 4; j++) { f32x4 z = {0.f, 0.f, 0.f, 0.f}; acc[i][j] = z; }

  for (int kt = 0; kt < K; kt += 32) {
    __syncthreads();
    gload16(pA, ldsA0);
    gload16(pA + (size_t)16 * K, ldsA1);
    gload16(pB, ldsB0);
    gload16(pB + (size_t)16 * K, ldsB1);
    pA += 32; pB += 32;
    __syncthreads();
    bf16x8 af[4], bv[4];
#pragma unroll
    for (int mt = 0; mt < 4; mt++) {
      int r = wm + mt * 16 + l;
      af[mt] = *(const bf16x8*)&As[r * 32 + ((quad ^ (r & 3)) * 8)];
    }
#pragma unroll
    for (int nt = 0; nt < 4; nt++) {
      int r = wn + nt * 16 + l;
      bv[nt] = *(const bf16x8*)&Bs[r * 32 + ((quad ^ (r & 3)) * 8)];
    }
#pragma unroll
    for (int mt = 0; mt < 4; mt++)
#pragma unroll
      for (int nt = 0; nt < 4; nt++)
        acc[mt][nt] = __builtin_amdgcn_mfma_f32_16x16x32_bf16(af[mt], bv[nt], acc[mt][nt], 0, 0, 0);
  }

  // epilogue: C/D layout col = lane&15, row = quad*4 + r
#pragma unroll
  for (int nt = 0; nt < 4; nt++) {
    const int col = bn * 128 + wn + nt * 16 + l;
#pragma unroll
    for (int mt = 0; mt < 4; mt++) {
      const int row0 = bm * 128 + wm + mt * 16 + quad * 4;
      if (MODE == 0) {
#pragma unroll
        for (int r = 0; r < 4; r++)
          Cout[(size_t)(row0 + r) * N + col] = acc[mt][nt][r];
      } else {
        const int bb = row0 >> 11, s = row0 & 2047;
        if (col < 2048) {
          unsigned short* dst = (col < 1024) ? Qb : Kb;
          const int c = col & 1023;
          const size_t off = ((size_t)(bb * 16 + (c >> 6)) * 2048 + s) * 64 + (c & 63);
#pragma unroll
          for (int r = 0; r < 4; r++)
            dst[off + (size_t)r * 64] = f32_bf16(acc[mt][nt][r]);
        } else {
          const int c = col - 2048;
          const size_t off = ((size_t)(bb * 16 + (c >> 6)) * 64 + (c & 63)) * 2048 + s;
          bf16x4 pk;
#pragma unroll
          for (int r = 0; r < 4; r++) pk[r] = (__bf16)acc[mt][nt][r];
          *(bf16x4*)&VTb[off] = pk;
        }
      }
    }
  }
}

// ---------------- fused flash attention, S^T formulation ----------------
// grid 512 = 16 q-tiles x 32 (b,h); block 256 = 4 waves, each owns 32 q-rows.
// S^T = K*Q^T so each lane's S elements all belong to q-row (lane&15):
// row-max/l are per-lane, P is written as packed b64 in A-fragment layout.
__global__ void __launch_bounds__(256, 2) attn(const unsigned short* __restrict__ Qb,
                                               const unsigned short* __restrict__ Kb,
                                               const unsigned short* __restrict__ VTb,
                                               const float* __restrict__ mask,
                                               const float* __restrict__ emb,
                                               const int* __restrict__ mflag,
                                               unsigned short* __restrict__ ctx) {
  __shared__ __align__(16) unsigned short Ks[128 * 64];
  __shared__ __align__(16) unsigned short VTs[64 * 128];
  __shared__ __align__(16) unsigned short Pb[4 * 32 * 136];  // per-wave P; head aliased for Q staging
  __shared__ float biasLUT[512];

  const float LOG2E = 1.4426950408889634f;
  const float c1 = 0.125f * LOG2E;       // 1/sqrt(64) * log2(e)
  const float C2 = 10000.0f * LOG2E;
  const int tid = threadIdx.x, wave = tid >> 6, lane = tid & 63;
  const int l = lane & 15, quad = lane >> 4;
  const int qt = blockIdx.x & 15, bh = blockIdx.x >> 4;
  const int b = bh >> 4, h = bh & 15;
  const int q0 = qt * 128;

  // bias LUT over rel in [-256, 255] (covers the 3 near-diagonal tiles)
  for (int i = tid; i < 512; i += 256) {
    int rel = i - 256;
    int rp = rel < 0 ? -rel : rel;
    int off = rp < 8 ? rp
                     : 8 + (rp >= 12) + (rp >= 16) + (rp >= 23) + (rp >= 32) +
                           (rp >= 46) + (rp >= 64) + (rp >= 91);
    int bucket = (rel > 0 ? 16 : 0) + off;
    biasLUT[i] = emb[bucket * 16 + h] * LOG2E;
  }
  const float satL = emb[15 * 16 + h] * LOG2E;
  const float satH = emb[31 * 16 + h] * LOG2E;
  const int masked = *mflag;

  const unsigned short* qb  = Qb  + ((size_t)(b * 16 + h) * 2048 + q0) * 64;
  const unsigned short* kb  = Kb  + (size_t)(b * 16 + h) * 2048 * 64;
  const unsigned short* vtb = VTb + (size_t)(b * 16 + h) * 64 * 2048;
  const float* mbase = mask + (size_t)b * 2048 * 2048;

  // ---- stage this wave's 32 Q rows into Pb head (consumed into regs before P writes) ----
  unsigned short* Qs = Pb;
  {
    const int rw = lane >> 3, c = lane & 7;
#pragma unroll
    for (int j = 0; j < 4; j++) {
      int row = wave * 32 + j * 8 + rw;
      gload16(qb + (size_t)row * 64 + ((c ^ (row & 7)) * 8), &Qs[(wave * 32 + j * 8) * 64]);
    }
  }
  __syncthreads();
  bf16x8 qf[2][2];
#pragma unroll
  for (int mtq = 0; mtq < 2; mtq++)
#pragma unroll
    for (int ks = 0; ks < 2; ks++) {
      int row = wave * 32 + mtq * 16 + l;
      qf[mtq][ks] = *(const bf16x8*)&Qs[row * 64 + (((ks * 4 + quad) ^ (row & 7)) * 8)];
    }

  float mr[2] = {-3.0e38f, -3.0e38f}, lr[2] = {0.f, 0.f};
  f32x4 Oa[2][4];
#pragma unroll
  for (int mt = 0; mt < 2; mt++)
#pragma unroll
    for (int dt = 0; dt < 4; dt++) { f32x4 z = {0.f, 0.f, 0.f, 0.f}; Oa[mt][dt] = z; }

  unsigned short* Pw = &Pb[wave * (32 * 136)];

  for (int kt = 0; kt < 16; kt++) {
    const int k0 = kt * 128;
    __syncthreads();  // prior Ks/VTs reads done (iter0: Q frag reads done)
    // ---- stage K tile (128 x 64), swizzled, pure async ----
    {
      const int rw = lane >> 3, c = lane & 7;
#pragma unroll
      for (int j = 0; j < 4; j++) {
        int row = wave * 32 + j * 8 + rw;
        gload16(kb + (size_t)(k0 + row) * 64 + ((c ^ (row & 7)) * 8),
                &Ks[(wave * 32 + j * 8) * 64]);
      }
    }
    // ---- stage V^T tile (64 d x 128 k), swizzled, pure async ----
    {
      const int rw = lane >> 4, c = lane & 15;
#pragma unroll
      for (int j = 0; j < 4; j++) {
        int drow = wave * 16 + j * 4 + rw;
        gload16(vtb + (size_t)drow * 2048 + k0 + ((c ^ (drow & 7)) * 8),
                &VTs[(wave * 16 + j * 4) * 128]);
      }
    }
    __syncthreads();

    // ---- S^T = K Q^T : D[k'][q'], k' = quad*4+r, q' = l ----
    f32x4 sa[2][8];
#pragma unroll
    for (int ntk = 0; ntk < 8; ntk++) {
      int row = ntk * 16 + l;
      bf16x8 kf0 = *(const bf16x8*)&Ks[row * 64 + ((quad ^ (row & 7)) * 8)];
      bf16x8 kf1 = *(const bf16x8*)&Ks[row * 64 + (((4 + quad) ^ (row & 7)) * 8)];
#pragma unroll
      for (int mtq = 0; mtq < 2; mtq++) {
        f32x4 z = {0.f, 0.f, 0.f, 0.f};
        z = __builtin_amdgcn_mfma_f32_16x16x32_bf16(kf0, qf[mtq][0], z, 0, 0, 0);
        z = __builtin_amdgcn_mfma_f32_16x16x32_bf16(kf1, qf[mtq][1], z, 0, 0, 0);
        sa[mtq][ntk] = z;
      }
    }

    // ---- scale + bias (+mask), per-lane row max ----
    const int d0 = k0 - q0;
    const bool sat = (d0 >= 256) || (d0 <= -256);
    const float bias_u = d0 > 0 ? satH : satL;
    const int ibase = 256 + d0 + quad * 4 - wave * 32 - l;
    float rmax[2];

    if (!masked) {
      if (sat) {
#pragma unroll
        for (int mtq = 0; mtq < 2; mtq++) {
          float tm = -3.0e38f;
#pragma unroll
          for (int ntk = 0; ntk < 8; ntk++) {
            f32x4 s = sa[mtq][ntk];
#pragma unroll
            for (int r = 0; r < 4; r++) s[r] = fmaf(s[r], c1, bias_u);
            sa[mtq][ntk] = s;
            tm = fmaxf(tm, fmaxf(fmaxf(s[0], s[1]), fmaxf(s[2], s[3])));
          }
          rmax[mtq] = tm;
        }
      } else {
#pragma unroll
        for (int mtq = 0; mtq < 2; mtq++) {
          float tm = -3.0e38f;
          const int ib = ibase - mtq * 16;
#pragma unroll
          for (int ntk = 0; ntk < 8; ntk++) {
            f32x4 s = sa[mtq][ntk];
#pragma unroll
            for (int r = 0; r < 4; r++)
              s[r] = fmaf(s[r], c1, biasLUT[ib + ntk * 16 + r]);
            sa[mtq][ntk] = s;
            tm = fmaxf(tm, fmaxf(fmaxf(s[0], s[1]), fmaxf(s[2], s[3])));
          }
          rmax[mtq] = tm;
        }
      }
    } else {
#pragma unroll
      for (int mtq = 0; mtq < 2; mtq++) {
        float tm = -3.0e38f;
        const int qg = q0 + wave * 32 + mtq * 16 + l;
        const int ib = ibase - mtq * 16;
#pragma unroll
        for (int ntk = 0; ntk < 8; ntk++) {
          const int kg = k0 + ntk * 16 + quad * 4;
          float4 mv4 = *(const float4*)&mbase[(size_t)qg * 2048 + kg];
          f32x4 s = sa[mtq][ntk];
#pragma unroll
          for (int r = 0; r < 4; r++) {
            float mv = r == 0 ? mv4.x : (r == 1 ? mv4.y : (r == 2 ? mv4.z : mv4.w));
            float bias = sat ? bias_u : biasLUT[ib + ntk * 16 + r];
            s[r] = fmaf(s[r], mv * c1, fmaf(mv, C2, bias - C2));
          }
          sa[mtq][ntk] = s;
          tm = fmaxf(tm, fmaxf(fmaxf(s[0], s[1]), fmaxf(s[2], s[3])));
        }
        rmax[mtq] = tm;
      }
    }

    // ---- cross-quad max (same q-row lives in lanes l, l+16, l+32, l+48) ----
    float alpha[2];
#pragma unroll
    for (int mtq = 0; mtq < 2; mtq++) {
      float v = rmax[mtq];
      v = fmaxf(v, __shfl_xor(v, 16));
      v = fmaxf(v, __shfl_xor(v, 32));
      float mn = fmaxf(mr[mtq], v);
      alpha[mtq] = __builtin_amdgcn_exp2f(mr[mtq] - mn);
      mr[mtq] = mn;
      lr[mtq] *= alpha[mtq];
    }

    // ---- P = exp2(s - m), packed b64 writes into A-frag layout P[q][k] ----
#pragma unroll
    for (int mtq = 0; mtq < 2; mtq++) {
      const float m = mr[mtq];
      float ls = 0.f;
#pragma unroll
      for (int ntk = 0; ntk < 8; ntk++) {
        f32x4 s = sa[mtq][ntk];
        bf16x4 pk;
        float p0 = __builtin_amdgcn_exp2f(s[0] - m);
        float p1 = __builtin_amdgcn_exp2f(s[1] - m);
        float p2 = __builtin_amdgcn_exp2f(s[2] - m);
        float p3 = __builtin_amdgcn_exp2f(s[3] - m);
        pk[0] = (__bf16)p0; pk[1] = (__bf16)p1; pk[2] = (__bf16)p2; pk[3] = (__bf16)p3;
        ls += (p0 + p1) + (p2 + p3);
        *(bf16x4*)&Pw[(mtq * 16 + l) * 136 + ntk * 16 + quad * 4] = pk;
      }
      lr[mtq] += ls;
    }

    // ---- rescale O accumulator (alpha broadcast from lane quad*4+r) ----
#pragma unroll
    for (int mt = 0; mt < 2; mt++)
#pragma unroll
      for (int r = 0; r < 4; r++) {
        float a_bc = bcast_lane(alpha[mt], quad * 4 + r);
#pragma unroll
        for (int dt = 0; dt < 4; dt++) Oa[mt][dt][r] *= a_bc;
      }

    // ---- O += P V (P wave-private: no barrier needed) ----
#pragma unroll
    for (int ks = 0; ks < 4; ks++) {
      bf16x8 pf[2], vf[4];
#pragma unroll
      for (int mtq = 0; mtq < 2; mtq++)
        pf[mtq] = *(const bf16x8*)&Pw[(mtq * 16 + l) * 136 + ks * 32 + quad * 8];
#pragma unroll
      for (int dt = 0; dt < 4; dt++) {
        int row = dt * 16 + l;
        vf[dt] = *(const bf16x8*)&VTs[row * 128 + (((ks * 4 + quad) ^ (row & 7)) * 8)];
      }
#pragma unroll
      for (int mtq = 0; mtq < 2; mtq++)
#pragma unroll
        for (int dt = 0; dt < 4; dt++)
          Oa[mtq][dt] = __builtin_amdgcn_mfma_f32_16x16x32_bf16(pf[mtq], vf[dt], Oa[mtq][dt], 0, 0, 0);
    }
  }

  // ---- finalize: l reduce across quads, normalize, store ----
  float inv[2];
#pragma unroll
  for (int mtq = 0; mtq < 2; mtq++) {
    float v = lr[mtq];
    v += __shfl_xor(v, 16);
    v += __shfl_xor(v, 32);
    inv[mtq] = 1.0f / v;
  }
#pragma unroll
  for (int mt = 0; mt < 2; mt++)
#pragma unroll
    for (int r = 0; r < 4; r++) {
      float i_bc = bcast_lane(inv[mt], quad * 4 + r);
      const int qg = q0 + wave * 32 + mt * 16 + quad * 4 + r;
#pragma unroll
      for (int dt = 0; dt < 4; dt++)
        ctx[(size_t)(b * 2048 + qg) * 1024 + h * 64 + dt * 16 + l] =
            f32_bf16(Oa[mt][dt][r] * i_bc);
    }
}

// ---------------- launch ----------------
extern "C" void kernel_launch(void* const* d_in, const int* in_sizes, int n_in,
                              void* d_out, int out_size, void* d_ws, size_t ws_size,
                              hipStream_t stream) {
  const float* hs   = (const float*)d_in[0];
  const float* mask = (const float*)d_in[1];
  const float* wqkv = (const float*)d_in[2];
  const float* wo   = (const float*)d_in[3];
  const float* emb  = (const float*)d_in[4];
  float* out = (float*)d_out;

  char* ws = (char*)d_ws;
  unsigned short* hB  = (unsigned short*)(ws);               //  8 MB (alias ctx)
  unsigned short* ctx = (unsigned short*)(ws);               //  alias
  unsigned short* wqT = (unsigned short*)(ws + 8388608);     //  6 MB
  unsigned short* woT = (unsigned short*)(ws + 14680064);    //  2 MB
  unsigned short* Qb  = (unsigned short*)(ws + 16777216);    //  8 MB  [b,h,s,d]
  unsigned short* Kb  = (unsigned short*)(ws + 25165824);    //  8 MB  [b,h,s,d]
  unsigned short* VTb = (unsigned short*)(ws + 33554432);    //  8 MB  [b,h,d,s]
  int* mflag          = (int*)(ws + 41943040);
  if (ws_size < 41943044) return;

  hipMemsetAsync(mflag, 0, 4, stream);
  cast_bf16<<<4096, 256, 0, stream>>>(hs, hB);
  transpose_cast<<<dim3(16, 48), 256, 0, stream>>>(wqkv, wqT, 1024, 3072);
  transpose_cast<<<dim3(16, 16), 256, 0, stream>>>(wo, woT, 1024, 1024);
  mask_check<<<8192, 256, 0, stream>>>(mask, mflag);
  gemm_bt<2><<<dim3(32, 24), 256, 0, stream>>>(hB, wqT, nullptr, Qb, Kb, VTb, 4096, 3072, 1024);
  attn<<<512, 256, 0, stream>>>(Qb, Kb, VTb, mask, emb, mflag, ctx);
  gemm_bt<0><<<dim3(32, 8), 256, 0, stream>>>(ctx, woT, out, nullptr, nullptr, nullptr, 4096, 1024, 1024);
}

// Round 3
// 235.139 us; speedup vs baseline: 1.6766x; 1.1086x over previous
//
#include <hip/hip_runtime.h>
#include <cstdint>

#define DEV static __device__ __forceinline__

typedef __bf16 bf16x8 __attribute__((ext_vector_type(8)));
typedef __bf16 bf16x4 __attribute__((ext_vector_type(4)));
typedef short  s16x4  __attribute__((ext_vector_type(4)));
typedef float  f32x4  __attribute__((ext_vector_type(4)));

DEV unsigned short f32_bf16(float f) {
  union { float f; unsigned u; } v; v.f = f;
  unsigned r = v.u + 0x7FFFu + ((v.u >> 16) & 1u);
  return (unsigned short)(r >> 16);
}

DEV void gload16(const void* g, void* lds) {
  __builtin_amdgcn_global_load_lds((__attribute__((address_space(1))) void*)g,
                                   (__attribute__((address_space(3))) void*)lds,
                                   16, 0, 0);
}

DEV float bcast_lane(float v, int srclane) {
  union { float f; int i; } u; u.f = v;
  u.i = __builtin_amdgcn_ds_bpermute(srclane << 2, u.i);
  return u.f;
}

// 16x16x16 bf16 MFMA: A[m=lane&15][k=quad*4+j], B[k=quad*4+j][n=lane&15],
// C/D col=lane&15 row=quad*4+r. P (from S^T C-layout) feeds A directly.
DEV f32x4 mfma16_bf16(bf16x4 a, bf16x4 b, f32x4 c) {
  union { bf16x4 h; s16x4 s; } ua, ub; ua.h = a; ub.h = b;
#if __has_builtin(__builtin_amdgcn_mfma_f32_16x16x16bf16_1k)
  return __builtin_amdgcn_mfma_f32_16x16x16bf16_1k(ua.s, ub.s, c, 0, 0, 0);
#else
  f32x4 d;
  asm("v_mfma_f32_16x16x16_bf16 %0, %1, %2, %3" : "=v"(d) : "v"(ua.s), "v"(ub.s), "v"(c));
  return d;
#endif
}

// ---------------- elementwise cast fp32 -> bf16 ----------------
__global__ void cast_bf16(const float* __restrict__ x, unsigned short* __restrict__ y) {
  int i = blockIdx.x * 256 + threadIdx.x;
  float4 v = ((const float4*)x)[i];
  uint2 o;
  o.x = (unsigned)f32_bf16(v.x) | ((unsigned)f32_bf16(v.y) << 16);
  o.y = (unsigned)f32_bf16(v.z) | ((unsigned)f32_bf16(v.w) << 16);
  ((uint2*)y)[i] = o;
}

// ---------------- tiled transpose-cast: W[K][N] fp32 -> WT[N][K] bf16 ----------------
__global__ void transpose_cast(const float* __restrict__ W, unsigned short* __restrict__ WT,
                               int K, int N) {
  __shared__ float t[64][65];
  int k0 = blockIdx.x * 64, n0 = blockIdx.y * 64;
  int tn = threadIdx.x & 63, tk = threadIdx.x >> 6;
#pragma unroll
  for (int i = 0; i < 64; i += 4)
    t[tk + i][tn] = W[(size_t)(k0 + tk + i) * N + n0 + tn];
  __syncthreads();
  int k2 = (threadIdx.x & 31) * 2, n = threadIdx.x >> 5;
#pragma unroll
  for (int i = 0; i < 64; i += 8) {
    int nn = n + i;
    unsigned o = (unsigned)f32_bf16(t[k2][nn]) | ((unsigned)f32_bf16(t[k2 + 1][nn]) << 16);
    *(unsigned*)&WT[(size_t)(n0 + nn) * K + k0 + k2] = o;
  }
}

// ---------------- mask uniformity check ----------------
__global__ void mask_check(const float* __restrict__ m, int* __restrict__ flag) {
  size_t i = ((size_t)blockIdx.x * 256 + threadIdx.x) * 4;
  float4 v = *(const float4*)(m + i);
  if (v.x != 1.0f || v.y != 1.0f || v.z != 1.0f || v.w != 1.0f) atomicOr(flag, 1);
}

// ---------------- GEMM: C[M][N] = A[M][K] * BT[N][K]^T ----------------
// MODE 0: fp32 C. MODE 2: scatter Qb/Kb [b,h,s,d], VTb [b,h,d,s] (TN must be 128).
// TN = 128 (4 waves 2x2, 64x64/wave) or 64 (4 waves 2x2, 64x32/wave).
template <int MODE, int TN>
__global__ void __launch_bounds__(256) gemm_bt(const unsigned short* __restrict__ A,
                                               const unsigned short* __restrict__ BT,
                                               float* __restrict__ Cout,
                                               unsigned short* __restrict__ Qb,
                                               unsigned short* __restrict__ Kb,
                                               unsigned short* __restrict__ VTb,
                                               int M, int N, int K) {
  constexpr int NT = TN / 32;
  __shared__ __align__(16) unsigned short As[128 * 32];
  __shared__ __align__(16) unsigned short Bs[TN * 32];
  const int tid = threadIdx.x, wave = tid >> 6, lane = tid & 63;
  const int l = lane & 15, quad = lane >> 4;
  const int wm = (wave & 1) * 64, wn = (wave >> 1) * (TN >> 1);
  const int bm = blockIdx.x, bn = blockIdx.y;

  const int srowA = wave * 32 + (lane >> 2);
  const int sswzA = ((lane & 3) ^ (srowA & 3)) * 8;
  const int srowB = (TN == 128) ? srowA : (wave * 16 + (lane >> 2));
  const int sswzB = ((lane & 3) ^ (srowB & 3)) * 8;
  const unsigned short* pA = A + (size_t)(bm * 128 + srowA) * K + sswzA;
  const unsigned short* pB = BT + (size_t)(bn * TN + srowB) * K + sswzB;
  unsigned short* ldsA0 = &As[(wave * 32) * 32];
  unsigned short* ldsA1 = &As[(wave * 32 + 16) * 32];
  unsigned short* ldsB0 = &Bs[((TN == 128 ? wave * 32 : wave * 16)) * 32];
  unsigned short* ldsB1 = &Bs[(wave * 32 + 16) * 32];  // TN==128 only

  f32x4 acc[4][NT];
#pragma unroll
  for (int i = 0; i < 4; i++)
#pragma unroll
    for (int j = 0; j < NT; j++) { f32x4 z = {0.f, 0.f, 0.f, 0.f}; acc[i][j] = z; }

  for (int kt = 0; kt < K; kt += 32) {
    __syncthreads();
    gload16(pA, ldsA0);
    gload16(pA + (size_t)16 * K, ldsA1);
    gload16(pB, ldsB0);
    if (TN == 128) gload16(pB + (size_t)16 * K, ldsB1);
    pA += 32; pB += 32;
    __syncthreads();
    bf16x8 af[4], bv[NT];
#pragma unroll
    for (int mt = 0; mt < 4; mt++) {
      int r = wm + mt * 16 + l;
      af[mt] = *(const bf16x8*)&As[r * 32 + ((quad ^ (r & 3)) * 8)];
    }
#pragma unroll
    for (int nt = 0; nt < NT; nt++) {
      int r = wn + nt * 16 + l;
      bv[nt] = *(const bf16x8*)&Bs[r * 32 + ((quad ^ (r & 3)) * 8)];
    }
#pragma unroll
    for (int mt = 0; mt < 4; mt++)
#pragma unroll
      for (int nt = 0; nt < NT; nt++)
        acc[mt][nt] = __builtin_amdgcn_mfma_f32_16x16x32_bf16(af[mt], bv[nt], acc[mt][nt], 0, 0, 0);
  }

  // epilogue: C/D layout col = lane&15, row = quad*4 + r
#pragma unroll
  for (int nt = 0; nt < NT; nt++) {
    const int col = bn * TN + wn + nt * 16 + l;
#pragma unroll
    for (int mt = 0; mt < 4; mt++) {
      const int row0 = bm * 128 + wm + mt * 16 + quad * 4;
      if (MODE == 0) {
#pragma unroll
        for (int r = 0; r < 4; r++)
          Cout[(size_t)(row0 + r) * N + col] = acc[mt][nt][r];
      } else {
        const int bb = row0 >> 11, s = row0 & 2047;
        if (col < 2048) {
          unsigned short* dst = (col < 1024) ? Qb : Kb;
          const int c = col & 1023;
          const size_t off = ((size_t)(bb * 16 + (c >> 6)) * 2048 + s) * 64 + (c & 63);
#pragma unroll
          for (int r = 0; r < 4; r++)
            dst[off + (size_t)r * 64] = f32_bf16(acc[mt][nt][r]);
        } else {
          const int c = col - 2048;
          const size_t off = ((size_t)(bb * 16 + (c >> 6)) * 64 + (c & 63)) * 2048 + s;
          bf16x4 pk;
#pragma unroll
          for (int r = 0; r < 4; r++) pk[r] = (__bf16)acc[mt][nt][r];
          *(bf16x4*)&VTb[off] = pk;
        }
      }
    }
  }
}

// ---------------- fused flash attention, S^T formulation, P-in-registers ----------------
// grid 512 = 16 q-tiles x 32 (b,h); block 256 = 4 waves x 32 q-rows.
// S^T = K*Q^T (C-layout: q=lane&15, k=quad*4+r) feeds PV's 16x16x16 A-frag directly.
// No online max: softmax is shift-invariant; clamp at 30 (exp2 domain) guards overflow.
__global__ void __launch_bounds__(256, 2) attn(const unsigned short* __restrict__ Qb,
                                               const unsigned short* __restrict__ Kb,
                                               const unsigned short* __restrict__ VTb,
                                               const float* __restrict__ mask,
                                               const float* __restrict__ emb,
                                               const int* __restrict__ mflag,
                                               unsigned short* __restrict__ ctx) {
  __shared__ __align__(16) unsigned short Ks[128 * 64];   // K tile (also Q staging pre-loop)
  __shared__ __align__(16) unsigned short VTs[64 * 128];  // V^T tile
  __shared__ float biasLUT[512];

  const float LOG2E = 1.4426950408889634f;
  const float c1 = 0.125f * LOG2E;
  const float C2 = 10000.0f * LOG2E;
  const int tid = threadIdx.x, wave = tid >> 6, lane = tid & 63;
  const int l = lane & 15, quad = lane >> 4;
  const int qt = blockIdx.x & 15, bh = blockIdx.x >> 4;
  const int b = bh >> 4, h = bh & 15;
  const int q0 = qt * 128;

  for (int i = tid; i < 512; i += 256) {
    int rel = i - 256;
    int rp = rel < 0 ? -rel : rel;
    int off = rp < 8 ? rp
                     : 8 + (rp >= 12) + (rp >= 16) + (rp >= 23) + (rp >= 32) +
                           (rp >= 46) + (rp >= 64) + (rp >= 91);
    int bucket = (rel > 0 ? 16 : 0) + off;
    biasLUT[i] = emb[bucket * 16 + h] * LOG2E;
  }
  const float satL = emb[15 * 16 + h] * LOG2E;
  const float satH = emb[31 * 16 + h] * LOG2E;
  const int masked = *mflag;

  const unsigned short* qb  = Qb  + ((size_t)(b * 16 + h) * 2048 + q0) * 64;
  const unsigned short* kb  = Kb  + (size_t)(b * 16 + h) * 2048 * 64;
  const unsigned short* vtb = VTb + (size_t)(b * 16 + h) * 64 * 2048;
  const float* mbase = mask + (size_t)b * 2048 * 2048;

  // ---- stage Q (128x64) into Ks region, read fragments to regs ----
  {
    const int rw = lane >> 3, c = lane & 7;
#pragma unroll
    for (int j = 0; j < 4; j++) {
      int row = wave * 32 + j * 8 + rw;
      gload16(qb + (size_t)row * 64 + ((c ^ (row & 7)) * 8), &Ks[(wave * 32 + j * 8) * 64]);
    }
  }
  __syncthreads();
  bf16x8 qf[2][2];
#pragma unroll
  for (int mtq = 0; mtq < 2; mtq++)
#pragma unroll
    for (int ks = 0; ks < 2; ks++) {
      int row = wave * 32 + mtq * 16 + l;
      qf[mtq][ks] = *(const bf16x8*)&Ks[row * 64 + (((ks * 4 + quad) ^ (row & 7)) * 8)];
    }

  float lr[2] = {0.f, 0.f};
  f32x4 Oa[2][4];
#pragma unroll
  for (int mt = 0; mt < 2; mt++)
#pragma unroll
    for (int dt = 0; dt < 4; dt++) { f32x4 z = {0.f, 0.f, 0.f, 0.f}; Oa[mt][dt] = z; }

  for (int kt = 0; kt < 16; kt++) {
    const int k0 = kt * 128;
    __syncthreads();  // prior Ks/VTs fragment reads done (iter0: Q frag reads done)
    // ---- stage K tile (128x64), swizzled ----
    {
      const int rw = lane >> 3, c = lane & 7;
#pragma unroll
      for (int j = 0; j < 4; j++) {
        int row = wave * 32 + j * 8 + rw;
        gload16(kb + (size_t)(k0 + row) * 64 + ((c ^ (row & 7)) * 8),
                &Ks[(wave * 32 + j * 8) * 64]);
      }
    }
    // ---- stage V^T tile (64 d x 128 k), swizzled ----
    {
      const int rw = lane >> 4, c = lane & 15;
#pragma unroll
      for (int j = 0; j < 4; j++) {
        int drow = wave * 16 + j * 4 + rw;
        gload16(vtb + (size_t)drow * 2048 + k0 + ((c ^ (drow & 7)) * 8),
                &VTs[(wave * 16 + j * 4) * 128]);
      }
    }
    __syncthreads();

    // ---- S^T = K Q^T, then scale+bias(+mask), exp2, pack P into A-frag regs ----
    const int d0 = k0 - q0;
    const bool sat = (d0 >= 256) || (d0 <= -256);
    const float bias_u = d0 > 0 ? satH : satL;
    const int ibase = 256 + d0 + quad * 4 - wave * 32 - l;
    bf16x4 pa[2][8];

#pragma unroll
    for (int ntk = 0; ntk < 8; ntk++) {
      int row = ntk * 16 + l;
      bf16x8 kf0 = *(const bf16x8*)&Ks[row * 64 + ((quad ^ (row & 7)) * 8)];
      bf16x8 kf1 = *(const bf16x8*)&Ks[row * 64 + (((4 + quad) ^ (row & 7)) * 8)];
#pragma unroll
      for (int mtq = 0; mtq < 2; mtq++) {
        f32x4 s = {0.f, 0.f, 0.f, 0.f};
        s = __builtin_amdgcn_mfma_f32_16x16x32_bf16(kf0, qf[mtq][0], s, 0, 0, 0);
        s = __builtin_amdgcn_mfma_f32_16x16x32_bf16(kf1, qf[mtq][1], s, 0, 0, 0);

        const int ib = ibase - mtq * 16 + ntk * 16;
        if (!masked) {
          if (sat) {
#pragma unroll
            for (int r = 0; r < 4; r++) s[r] = fmaf(s[r], c1, bias_u);
          } else {
#pragma unroll
            for (int r = 0; r < 4; r++) s[r] = fmaf(s[r], c1, biasLUT[ib + r]);
          }
        } else {
          const int qg = q0 + wave * 32 + mtq * 16 + l;
          const int kg = k0 + ntk * 16 + quad * 4;
          float4 mv4 = *(const float4*)&mbase[(size_t)qg * 2048 + kg];
#pragma unroll
          for (int r = 0; r < 4; r++) {
            float mv = r == 0 ? mv4.x : (r == 1 ? mv4.y : (r == 2 ? mv4.z : mv4.w));
            float bias = sat ? bias_u : biasLUT[ib + r];
            s[r] = fmaf(s[r], mv * c1, fmaf(mv, C2, bias - C2));
          }
        }
        bf16x4 pk;
        float ls = 0.f;
#pragma unroll
        for (int r = 0; r < 4; r++) {
          float p = __builtin_amdgcn_exp2f(fminf(s[r], 30.0f));
          ls += p;
          pk[r] = (__bf16)p;
        }
        lr[mtq] += ls;
        pa[mtq][ntk] = pk;
      }
    }

    // ---- O += P V via 16x16x16 MFMA (P straight from registers) ----
#pragma unroll
    for (int ntk = 0; ntk < 8; ntk++) {
      bf16x4 vf[4];
#pragma unroll
      for (int dt = 0; dt < 4; dt++) {
        int row = dt * 16 + l;
        int ch = (ntk * 2 + (quad >> 1)) ^ (l & 7);
        vf[dt] = *(const bf16x4*)&VTs[row * 128 + ch * 8 + (quad & 1) * 4];
      }
#pragma unroll
      for (int mtq = 0; mtq < 2; mtq++)
#pragma unroll
        for (int dt = 0; dt < 4; dt++)
          Oa[mtq][dt] = mfma16_bf16(pa[mtq][ntk], vf[dt], Oa[mtq][dt]);
    }
  }

  // ---- finalize: l cross-quad sum, normalize, store ----
  float inv[2];
#pragma unroll
  for (int mtq = 0; mtq < 2; mtq++) {
    float v = lr[mtq];
    v += __shfl_xor(v, 16);
    v += __shfl_xor(v, 32);
    inv[mtq] = 1.0f / v;
  }
#pragma unroll
  for (int mt = 0; mt < 2; mt++)
#pragma unroll
    for (int r = 0; r < 4; r++) {
      float i_bc = bcast_lane(inv[mt], quad * 4 + r);
      const int qg = q0 + wave * 32 + mt * 16 + quad * 4 + r;
#pragma unroll
      for (int dt = 0; dt < 4; dt++)
        ctx[(size_t)(b * 2048 + qg) * 1024 + h * 64 + dt * 16 + l] =
            f32_bf16(Oa[mt][dt][r] * i_bc);
    }
}

// ---------------- launch ----------------
extern "C" void kernel_launch(void* const* d_in, const int* in_sizes, int n_in,
                              void* d_out, int out_size, void* d_ws, size_t ws_size,
                              hipStream_t stream) {
  const float* hs   = (const float*)d_in[0];
  const float* mask = (const float*)d_in[1];
  const float* wqkv = (const float*)d_in[2];
  const float* wo   = (const float*)d_in[3];
  const float* emb  = (const float*)d_in[4];
  float* out = (float*)d_out;

  char* ws = (char*)d_ws;
  unsigned short* hB  = (unsigned short*)(ws);               //  8 MB (alias ctx)
  unsigned short* ctx = (unsigned short*)(ws);               //  alias
  unsigned short* wqT = (unsigned short*)(ws + 8388608);     //  6 MB
  unsigned short* woT = (unsigned short*)(ws + 14680064);    //  2 MB
  unsigned short* Qb  = (unsigned short*)(ws + 16777216);    //  8 MB  [b,h,s,d]
  unsigned short* Kb  = (unsigned short*)(ws + 25165824);    //  8 MB  [b,h,s,d]
  unsigned short* VTb = (unsigned short*)(ws + 33554432);    //  8 MB  [b,h,d,s]
  int* mflag          = (int*)(ws + 41943040);
  if (ws_size < 41943044) return;

  hipMemsetAsync(mflag, 0, 4, stream);
  cast_bf16<<<4096, 256, 0, stream>>>(hs, hB);
  transpose_cast<<<dim3(16, 48), 256, 0, stream>>>(wqkv, wqT, 1024, 3072);
  transpose_cast<<<dim3(16, 16), 256, 0, stream>>>(wo, woT, 1024, 1024);
  mask_check<<<8192, 256, 0, stream>>>(mask, mflag);
  gemm_bt<2, 128><<<dim3(32, 24), 256, 0, stream>>>(hB, wqT, nullptr, Qb, Kb, VTb, 4096, 3072, 1024);
  attn<<<512, 256, 0, stream>>>(Qb, Kb, VTb, mask, emb, mflag, ctx);
  gemm_bt<0, 64><<<dim3(32, 16), 256, 0, stream>>>(ctx, woT, out, nullptr, nullptr, nullptr, 4096, 1024, 1024);
}

// Round 4
// 225.212 us; speedup vs baseline: 1.7505x; 1.0441x over previous
//
#include <hip/hip_runtime.h>
#include <cstdint>

#define DEV static __device__ __forceinline__

typedef __bf16 bf16x8 __attribute__((ext_vector_type(8)));
typedef __bf16 bf16x4 __attribute__((ext_vector_type(4)));
typedef short  s16x4  __attribute__((ext_vector_type(4)));
typedef float  f32x4  __attribute__((ext_vector_type(4)));

DEV unsigned short f32_bf16(float f) {
  union { float f; unsigned u; } v; v.f = f;
  unsigned r = v.u + 0x7FFFu + ((v.u >> 16) & 1u);
  return (unsigned short)(r >> 16);
}

DEV void gload16(const void* g, void* lds) {
  __builtin_amdgcn_global_load_lds((__attribute__((address_space(1))) void*)g,
                                   (__attribute__((address_space(3))) void*)lds,
                                   16, 0, 0);
}

DEV float bcast_lane(float v, int srclane) {
  union { float f; int i; } u; u.f = v;
  u.i = __builtin_amdgcn_ds_bpermute(srclane << 2, u.i);
  return u.f;
}

// 16x16x16 bf16 MFMA: A[m=lane&15][k=quad*4+j], B[k=quad*4+j][n=lane&15],
// C/D col=lane&15 row=quad*4+r. P (from S^T C-layout) feeds A directly.
DEV f32x4 mfma16_bf16(bf16x4 a, bf16x4 b, f32x4 c) {
  union { bf16x4 h; s16x4 s; } ua, ub; ua.h = a; ub.h = b;
#if __has_builtin(__builtin_amdgcn_mfma_f32_16x16x16bf16_1k)
  return __builtin_amdgcn_mfma_f32_16x16x16bf16_1k(ua.s, ub.s, c, 0, 0, 0);
#else
  f32x4 d;
  asm("v_mfma_f32_16x16x16_bf16 %0, %1, %2, %3" : "=v"(d) : "v"(ua.s), "v"(ub.s), "v"(c));
  return d;
#endif
}

// ---------------- elementwise cast fp32 -> bf16 ----------------
__global__ void cast_bf16(const float* __restrict__ x, unsigned short* __restrict__ y) {
  int i = blockIdx.x * 256 + threadIdx.x;
  float4 v = ((const float4*)x)[i];
  uint2 o;
  o.x = (unsigned)f32_bf16(v.x) | ((unsigned)f32_bf16(v.y) << 16);
  o.y = (unsigned)f32_bf16(v.z) | ((unsigned)f32_bf16(v.w) << 16);
  ((uint2*)y)[i] = o;
}

// ---------------- tiled transpose-cast: W[K][N] fp32 -> WT[N][K] bf16 ----------------
__global__ void transpose_cast(const float* __restrict__ W, unsigned short* __restrict__ WT,
                               int K, int N) {
  __shared__ float t[64][65];
  int k0 = blockIdx.x * 64, n0 = blockIdx.y * 64;
  int tn = threadIdx.x & 63, tk = threadIdx.x >> 6;
#pragma unroll
  for (int i = 0; i < 64; i += 4)
    t[tk + i][tn] = W[(size_t)(k0 + tk + i) * N + n0 + tn];
  __syncthreads();
  int k2 = (threadIdx.x & 31) * 2, n = threadIdx.x >> 5;
#pragma unroll
  for (int i = 0; i < 64; i += 8) {
    int nn = n + i;
    unsigned o = (unsigned)f32_bf16(t[k2][nn]) | ((unsigned)f32_bf16(t[k2 + 1][nn]) << 16);
    *(unsigned*)&WT[(size_t)(n0 + nn) * K + k0 + k2] = o;
  }
}

// ---------------- mask uniformity check ----------------
__global__ void mask_check(const float* __restrict__ m, int* __restrict__ flag) {
  size_t i = ((size_t)blockIdx.x * 256 + threadIdx.x) * 4;
  float4 v = *(const float4*)(m + i);
  if (v.x != 1.0f || v.y != 1.0f || v.z != 1.0f || v.w != 1.0f) atomicOr(flag, 1);
}

// ---------------- GEMM: C[M][N] = A[M][K] * BT[N][K]^T ----------------
// MODE 0: fp32 C. MODE 2: scatter Qb/Kb [b,h,s,d], VTb [b,h,d,s] (TN must be 128).
template <int MODE, int TN>
__global__ void __launch_bounds__(256) gemm_bt(const unsigned short* __restrict__ A,
                                               const unsigned short* __restrict__ BT,
                                               float* __restrict__ Cout,
                                               unsigned short* __restrict__ Qb,
                                               unsigned short* __restrict__ Kb,
                                               unsigned short* __restrict__ VTb,
                                               int M, int N, int K) {
  constexpr int NT = TN / 32;
  __shared__ __align__(16) unsigned short As[128 * 32];
  __shared__ __align__(16) unsigned short Bs[TN * 32];
  const int tid = threadIdx.x, wave = tid >> 6, lane = tid & 63;
  const int l = lane & 15, quad = lane >> 4;
  const int wm = (wave & 1) * 64, wn = (wave >> 1) * (TN >> 1);
  const int bm = blockIdx.x, bn = blockIdx.y;

  const int srowA = wave * 32 + (lane >> 2);
  const int sswzA = ((lane & 3) ^ (srowA & 3)) * 8;
  const int srowB = (TN == 128) ? srowA : (wave * 16 + (lane >> 2));
  const int sswzB = ((lane & 3) ^ (srowB & 3)) * 8;
  const unsigned short* pA = A + (size_t)(bm * 128 + srowA) * K + sswzA;
  const unsigned short* pB = BT + (size_t)(bn * TN + srowB) * K + sswzB;
  unsigned short* ldsA0 = &As[(wave * 32) * 32];
  unsigned short* ldsA1 = &As[(wave * 32 + 16) * 32];
  unsigned short* ldsB0 = &Bs[((TN == 128 ? wave * 32 : wave * 16)) * 32];
  unsigned short* ldsB1 = &Bs[(wave * 32 + 16) * 32];  // TN==128 only

  f32x4 acc[4][NT];
#pragma unroll
  for (int i = 0; i < 4; i++)
#pragma unroll
    for (int j = 0; j < NT; j++) { f32x4 z = {0.f, 0.f, 0.f, 0.f}; acc[i][j] = z; }

  for (int kt = 0; kt < K; kt += 32) {
    __syncthreads();
    gload16(pA, ldsA0);
    gload16(pA + (size_t)16 * K, ldsA1);
    gload16(pB, ldsB0);
    if (TN == 128) gload16(pB + (size_t)16 * K, ldsB1);
    pA += 32; pB += 32;
    __syncthreads();
    bf16x8 af[4], bv[NT];
#pragma unroll
    for (int mt = 0; mt < 4; mt++) {
      int r = wm + mt * 16 + l;
      af[mt] = *(const bf16x8*)&As[r * 32 + ((quad ^ (r & 3)) * 8)];
    }
#pragma unroll
    for (int nt = 0; nt < NT; nt++) {
      int r = wn + nt * 16 + l;
      bv[nt] = *(const bf16x8*)&Bs[r * 32 + ((quad ^ (r & 3)) * 8)];
    }
#pragma unroll
    for (int mt = 0; mt < 4; mt++)
#pragma unroll
      for (int nt = 0; nt < NT; nt++)
        acc[mt][nt] = __builtin_amdgcn_mfma_f32_16x16x32_bf16(af[mt], bv[nt], acc[mt][nt], 0, 0, 0);
  }

  // epilogue: C/D layout col = lane&15, row = quad*4 + r
#pragma unroll
  for (int nt = 0; nt < NT; nt++) {
    const int col = bn * TN + wn + nt * 16 + l;
#pragma unroll
    for (int mt = 0; mt < 4; mt++) {
      const int row0 = bm * 128 + wm + mt * 16 + quad * 4;
      if (MODE == 0) {
#pragma unroll
        for (int r = 0; r < 4; r++)
          Cout[(size_t)(row0 + r) * N + col] = acc[mt][nt][r];
      } else {
        const int bb = row0 >> 11, s = row0 & 2047;
        if (col < 2048) {
          unsigned short* dst = (col < 1024) ? Qb : Kb;
          const int c = col & 1023;
          const size_t off = ((size_t)(bb * 16 + (c >> 6)) * 2048 + s) * 64 + (c & 63);
#pragma unroll
          for (int r = 0; r < 4; r++)
            dst[off + (size_t)r * 64] = f32_bf16(acc[mt][nt][r]);
        } else {
          const int c = col - 2048;
          const size_t off = ((size_t)(bb * 16 + (c >> 6)) * 64 + (c & 63)) * 2048 + s;
          bf16x4 pk;
#pragma unroll
          for (int r = 0; r < 4; r++) pk[r] = (__bf16)acc[mt][nt][r];
          *(bf16x4*)&VTb[off] = pk;
        }
      }
    }
  }
}

// ---------------- fused flash attention, S^T form, P-in-registers, double-buffered ----------------
// grid 512 = 16 q-tiles x 32 (b,h); block 256 = 4 waves x 32 q-rows.
// One barrier per K-iteration: tile kt+2 is staged into the buffer consumed at iter kt,
// right after the barrier, so its loads have a full compute phase to land (no vmcnt-drain stall).
__global__ void __launch_bounds__(256, 2) attn(const unsigned short* __restrict__ Qb,
                                               const unsigned short* __restrict__ Kb,
                                               const unsigned short* __restrict__ VTb,
                                               const float* __restrict__ mask,
                                               const float* __restrict__ emb,
                                               const int* __restrict__ mflag,
                                               unsigned short* __restrict__ ctx) {
  // two buffers, each: K tile (128x64) + V^T tile (64x128)
  __shared__ __align__(16) unsigned short KV[2][16384];
  __shared__ float biasLUT[512];

  const float LOG2E = 1.4426950408889634f;
  const float c1 = 0.125f * LOG2E;
  const float C2 = 10000.0f * LOG2E;
  const int tid = threadIdx.x, wave = tid >> 6, lane = tid & 63;
  const int l = lane & 15, quad = lane >> 4;
  const int qt = blockIdx.x & 15, bh = blockIdx.x >> 4;
  const int b = bh >> 4, h = bh & 15;
  const int q0 = qt * 128;

  for (int i = tid; i < 512; i += 256) {
    int rel = i - 256;
    int rp = rel < 0 ? -rel : rel;
    int off = rp < 8 ? rp
                     : 8 + (rp >= 12) + (rp >= 16) + (rp >= 23) + (rp >= 32) +
                           (rp >= 46) + (rp >= 64) + (rp >= 91);
    int bucket = (rel > 0 ? 16 : 0) + off;
    biasLUT[i] = emb[bucket * 16 + h] * LOG2E;
  }
  const float satL = emb[15 * 16 + h] * LOG2E;
  const float satH = emb[31 * 16 + h] * LOG2E;
  const int masked = *mflag;

  const unsigned short* qb  = Qb  + ((size_t)(b * 16 + h) * 2048 + q0) * 64;
  const unsigned short* kb  = Kb  + (size_t)(b * 16 + h) * 2048 * 64;
  const unsigned short* vtb = VTb + (size_t)(b * 16 + h) * 64 * 2048;
  const float* mbase = mask + (size_t)b * 2048 * 2048;

  const int rw8 = lane >> 3, c8 = lane & 7;     // K/Q staging: 8 chunks/row
  const int rw16 = lane >> 4, c16 = lane & 15;  // V staging: 16 chunks/row

  // ---- prologue: Q -> buf1 K-region, tile0 K/V -> buf0 ----
#pragma unroll
  for (int j = 0; j < 4; j++) {
    int row = wave * 32 + j * 8 + rw8;
    gload16(qb + (size_t)row * 64 + ((c8 ^ (row & 7)) * 8), &KV[1][(wave * 32 + j * 8) * 64]);
  }
#pragma unroll
  for (int j = 0; j < 4; j++) {
    int row = wave * 32 + j * 8 + rw8;
    gload16(kb + (size_t)row * 64 + ((c8 ^ (row & 7)) * 8), &KV[0][(wave * 32 + j * 8) * 64]);
  }
#pragma unroll
  for (int j = 0; j < 4; j++) {
    int drow = wave * 16 + j * 4 + rw16;
    gload16(vtb + (size_t)drow * 2048 + ((c16 ^ (drow & 7)) * 8),
            &KV[0][8192 + (wave * 16 + j * 4) * 128]);
  }
  __syncthreads();

  // each wave reads its own 32 Q rows (self-staged region of buf1)
  bf16x8 qf[2][2];
#pragma unroll
  for (int mtq = 0; mtq < 2; mtq++)
#pragma unroll
    for (int ks = 0; ks < 2; ks++) {
      int row = wave * 32 + mtq * 16 + l;
      qf[mtq][ks] = *(const bf16x8*)&KV[1][row * 64 + (((ks * 4 + quad) ^ (row & 7)) * 8)];
    }
  __syncthreads();  // Q reads complete before buf1 is overwritten with tile1

  // ---- stage tile1 -> buf1 ----
#pragma unroll
  for (int j = 0; j < 4; j++) {
    int row = wave * 32 + j * 8 + rw8;
    gload16(kb + (size_t)(128 + row) * 64 + ((c8 ^ (row & 7)) * 8),
            &KV[1][(wave * 32 + j * 8) * 64]);
  }
#pragma unroll
  for (int j = 0; j < 4; j++) {
    int drow = wave * 16 + j * 4 + rw16;
    gload16(vtb + (size_t)drow * 2048 + 128 + ((c16 ^ (drow & 7)) * 8),
            &KV[1][8192 + (wave * 16 + j * 4) * 128]);
  }

  float lr[2] = {0.f, 0.f};
  f32x4 Oa[2][4];
#pragma unroll
  for (int mt = 0; mt < 2; mt++)
#pragma unroll
    for (int dt = 0; dt < 4; dt++) { f32x4 z = {0.f, 0.f, 0.f, 0.f}; Oa[mt][dt] = z; }

  for (int kt = 0; kt < 16; kt++) {
    const int k0 = kt * 128;
    const unsigned short* Ks  = KV[kt & 1];
    const unsigned short* VTs = KV[kt & 1] + 8192;

    // ---- S^T = K Q^T, scale+bias(+mask), exp2, pack P into A-frag regs ----
    const int d0 = k0 - q0;
    const bool sat = (d0 >= 256) || (d0 <= -256);
    const float bias_u = d0 > 0 ? satH : satL;
    const int ibase = 256 + d0 + quad * 4 - wave * 32 - l;
    bf16x4 pa[2][8];

#pragma unroll
    for (int ntk = 0; ntk < 8; ntk++) {
      int row = ntk * 16 + l;
      bf16x8 kf0 = *(const bf16x8*)&Ks[row * 64 + ((quad ^ (row & 7)) * 8)];
      bf16x8 kf1 = *(const bf16x8*)&Ks[row * 64 + (((4 + quad) ^ (row & 7)) * 8)];
#pragma unroll
      for (int mtq = 0; mtq < 2; mtq++) {
        f32x4 s = {0.f, 0.f, 0.f, 0.f};
        s = __builtin_amdgcn_mfma_f32_16x16x32_bf16(kf0, qf[mtq][0], s, 0, 0, 0);
        s = __builtin_amdgcn_mfma_f32_16x16x32_bf16(kf1, qf[mtq][1], s, 0, 0, 0);

        const int ib = ibase - mtq * 16 + ntk * 16;
        if (!masked) {
          if (sat) {
#pragma unroll
            for (int r = 0; r < 4; r++) s[r] = fmaf(s[r], c1, bias_u);
          } else {
#pragma unroll
            for (int r = 0; r < 4; r++) s[r] = fmaf(s[r], c1, biasLUT[ib + r]);
          }
        } else {
          const int qg = q0 + wave * 32 + mtq * 16 + l;
          const int kg = k0 + ntk * 16 + quad * 4;
          float4 mv4 = *(const float4*)&mbase[(size_t)qg * 2048 + kg];
#pragma unroll
          for (int r = 0; r < 4; r++) {
            float mv = r == 0 ? mv4.x : (r == 1 ? mv4.y : (r == 2 ? mv4.z : mv4.w));
            float bias = sat ? bias_u : biasLUT[ib + r];
            s[r] = fmaf(s[r], mv * c1, fmaf(mv, C2, bias - C2));
          }
        }
        bf16x4 pk;
        float ls = 0.f;
#pragma unroll
        for (int r = 0; r < 4; r++) {
          float p = __builtin_amdgcn_exp2f(s[r]);  // softmax shift-invariance: no max needed
          ls += p;
          pk[r] = (__bf16)p;
        }
        lr[mtq] += ls;
        pa[mtq][ntk] = pk;
      }
    }

    // ---- O += P V via 16x16x16 MFMA (P straight from registers) ----
#pragma unroll
    for (int ntk = 0; ntk < 8; ntk++) {
      bf16x4 vf[4];
#pragma unroll
      for (int dt = 0; dt < 4; dt++) {
        int row = dt * 16 + l;
        int ch = (ntk * 2 + (quad >> 1)) ^ (l & 7);
        vf[dt] = *(const bf16x4*)&VTs[row * 128 + ch * 8 + (quad & 1) * 4];
      }
#pragma unroll
      for (int mtq = 0; mtq < 2; mtq++)
#pragma unroll
        for (int dt = 0; dt < 4; dt++)
          Oa[mtq][dt] = mfma16_bf16(pa[mtq][ntk], vf[dt], Oa[mtq][dt]);
    }

    // ---- one barrier: all reads of this buffer done + next tile's loads landed ----
    __syncthreads();
    if (kt + 2 < 16) {
      const int kn = (kt + 2) * 128;
      unsigned short* dst = (unsigned short*)KV[kt & 1];
#pragma unroll
      for (int j = 0; j < 4; j++) {
        int row = wave * 32 + j * 8 + rw8;
        gload16(kb + (size_t)(kn + row) * 64 + ((c8 ^ (row & 7)) * 8),
                &dst[(wave * 32 + j * 8) * 64]);
      }
#pragma unroll
      for (int j = 0; j < 4; j++) {
        int drow = wave * 16 + j * 4 + rw16;
        gload16(vtb + (size_t)drow * 2048 + kn + ((c16 ^ (drow & 7)) * 8),
                &dst[8192 + (wave * 16 + j * 4) * 128]);
      }
    }
  }

  // ---- finalize: l cross-quad sum, normalize, store ----
  float inv[2];
#pragma unroll
  for (int mtq = 0; mtq < 2; mtq++) {
    float v = lr[mtq];
    v += __shfl_xor(v, 16);
    v += __shfl_xor(v, 32);
    inv[mtq] = 1.0f / v;
  }
#pragma unroll
  for (int mt = 0; mt < 2; mt++)
#pragma unroll
    for (int r = 0; r < 4; r++) {
      float i_bc = bcast_lane(inv[mt], quad * 4 + r);
      const int qg = q0 + wave * 32 + mt * 16 + quad * 4 + r;
#pragma unroll
      for (int dt = 0; dt < 4; dt++)
        ctx[(size_t)(b * 2048 + qg) * 1024 + h * 64 + dt * 16 + l] =
            f32_bf16(Oa[mt][dt][r] * i_bc);
    }
}

// ---------------- launch ----------------
extern "C" void kernel_launch(void* const* d_in, const int* in_sizes, int n_in,
                              void* d_out, int out_size, void* d_ws, size_t ws_size,
                              hipStream_t stream) {
  const float* hs   = (const float*)d_in[0];
  const float* mask = (const float*)d_in[1];
  const float* wqkv = (const float*)d_in[2];
  const float* wo   = (const float*)d_in[3];
  const float* emb  = (const float*)d_in[4];
  float* out = (float*)d_out;

  char* ws = (char*)d_ws;
  unsigned short* hB  = (unsigned short*)(ws);               //  8 MB (alias ctx)
  unsigned short* ctx = (unsigned short*)(ws);               //  alias
  unsigned short* wqT = (unsigned short*)(ws + 8388608);     //  6 MB
  unsigned short* woT = (unsigned short*)(ws + 14680064);    //  2 MB
  unsigned short* Qb  = (unsigned short*)(ws + 16777216);    //  8 MB  [b,h,s,d]
  unsigned short* Kb  = (unsigned short*)(ws + 25165824);    //  8 MB  [b,h,s,d]
  unsigned short* VTb = (unsigned short*)(ws + 33554432);    //  8 MB  [b,h,d,s]
  int* mflag          = (int*)(ws + 41943040);
  if (ws_size < 41943044) return;

  hipMemsetAsync(mflag, 0, 4, stream);
  cast_bf16<<<4096, 256, 0, stream>>>(hs, hB);
  transpose_cast<<<dim3(16, 48), 256, 0, stream>>>(wqkv, wqT, 1024, 3072);
  transpose_cast<<<dim3(16, 16), 256, 0, stream>>>(wo, woT, 1024, 1024);
  mask_check<<<8192, 256, 0, stream>>>(mask, mflag);
  gemm_bt<2, 128><<<dim3(32, 24), 256, 0, stream>>>(hB, wqT, nullptr, Qb, Kb, VTb, 4096, 3072, 1024);
  attn<<<512, 256, 0, stream>>>(Qb, Kb, VTb, mask, emb, mflag, ctx);
  gemm_bt<0, 64><<<dim3(32, 16), 256, 0, stream>>>(ctx, woT, out, nullptr, nullptr, nullptr, 4096, 1024, 1024);
}